// Round 1
// baseline (229.901 us; speedup 1.0000x reference)
//
#include <hip/hip_runtime.h>
#include <hip/hip_bf16.h>

// STU spectral conv on MI355X.
// out[b,t,d] = 2 * sum_{j even, j<=t} phi_proj[j,d] * x_proj[b,t-j,d]
// Even/odd time split -> two length-2048 causal convs per (b,d), same real
// filter h[m]=phi_proj[2m,d]. Pack even seq as Re, odd as Im of one complex
// signal; one FFT-4096 -> xH_d -> IFFT-4096 yields both convs.
// DIF (natural->bitrev) forward, pointwise mult in bitrev order (H stored
// bitrev), DIT (bitrev->natural) inverse: no bit-reversal pass needed.

#define NB 4
#define NS 4096
#define ND 768
#define NK 24

typedef __attribute__((ext_vector_type(8))) short short8;
typedef __attribute__((ext_vector_type(4))) float f32x4;
typedef __attribute__((ext_vector_type(4))) unsigned short u16x4;

static __device__ __forceinline__ float bf2f(unsigned short u) {
  union { unsigned int i; float f; } v; v.i = ((unsigned int)u) << 16; return v.f;
}
static __device__ __forceinline__ unsigned short f2bf(float f) {
  union { float f; unsigned int i; } v; v.f = f;
  return (unsigned short)((v.i + 0x7fffu + ((v.i >> 16) & 1u)) >> 16);
}

// ---------------- cast x (fp32 -> bf16) ----------------
__global__ __launch_bounds__(256) void cast_x_bf16(const float* __restrict__ in,
                                                   unsigned short* __restrict__ out) {
  int i = (blockIdx.x * 256 + threadIdx.x) * 4;
  float4 v = *(const float4*)(in + i);
  u16x4 o = { f2bf(v.x), f2bf(v.y), f2bf(v.z), f2bf(v.w) };
  *(u16x4*)(out + i) = o;
}

// ---------------- MiT[d][e] = bf16(Mi[e][d]) ----------------
__global__ __launch_bounds__(256) void transpose_cast_Mi(const float* __restrict__ Mi,
                                                         unsigned short* __restrict__ MiT) {
  int idx = blockIdx.x * 256 + threadIdx.x;   // d*768 + e
  int d = idx / ND, e = idx % ND;
  MiT[idx] = f2bf(Mi[e * ND + d]);
}

// ---------------- phi_projT[d][s] = sum_k phi[s,k] Mf[k,d] (fp32) ----------------
__global__ __launch_bounds__(256) void phi_proj_kernel(const float* __restrict__ phi,
                                                       const float* __restrict__ Mf,
                                                       float* __restrict__ phiT) {
  int d = blockIdx.y;
  int s = blockIdx.x * 256 + threadIdx.x;
  float acc = 0.f;
#pragma unroll
  for (int k = 0; k < NK; ++k) acc += phi[s * NK + k] * Mf[k * ND + d];
  phiT[d * NS + s] = acc;
}

// ---------------- GEMM: x_projT[b,d,s] = bf16( sum_e x[b,s,e] Mi[e,d] ) ----------------
// A = x rows [16384,768] bf16, B^T = MiT [768,768] bf16 (d-major, k-contig).
// 128x128 tile, BK=32, 4 waves (2x2 of 64x64), mfma 16x16x32 bf16.
__global__ __launch_bounds__(256) void gemm_xprojT(const unsigned short* __restrict__ Xb,
                                                   const unsigned short* __restrict__ MiT,
                                                   unsigned short* __restrict__ XPT) {
  __shared__ unsigned short As[128 * 32];
  __shared__ unsigned short Bs[128 * 32];
  const int tid = threadIdx.x;
  const int r0 = blockIdx.x * 128;      // global row in [0,16384)
  const int c0 = blockIdx.y * 128;      // d
  const int lane = tid & 63;
  const int wave = tid >> 6;
  const int wr = (wave >> 1) * 64;
  const int wc = (wave & 1) * 64;

  f32x4 acc[4][4];
#pragma unroll
  for (int m = 0; m < 4; ++m)
#pragma unroll
    for (int n = 0; n < 4; ++n) acc[m][n] = (f32x4){0.f, 0.f, 0.f, 0.f};

  for (int k0 = 0; k0 < ND; k0 += 32) {
    // reg-staged (round-1 compile-safe; switch to global_load_lds later)
    short8 va[2], vb[2];
#pragma unroll
    for (int i = 0; i < 2; ++i) {
      int slot = tid + 256 * i;
      int row = slot >> 2, kc = slot & 3;
      va[i] = *(const short8*)(Xb + (size_t)(r0 + row) * ND + k0 + kc * 8);
      vb[i] = *(const short8*)(MiT + (size_t)(c0 + row) * ND + k0 + kc * 8);
    }
    __syncthreads();
#pragma unroll
    for (int i = 0; i < 2; ++i) {
      int slot = tid + 256 * i;
      *(short8*)(As + slot * 8) = va[i];
      *(short8*)(Bs + slot * 8) = vb[i];
    }
    __syncthreads();

    short8 a[4], b[4];
#pragma unroll
    for (int m = 0; m < 4; ++m)
      a[m] = *(const short8*)(As + (wr + m * 16 + (lane & 15)) * 32 + (lane >> 4) * 8);
#pragma unroll
    for (int n = 0; n < 4; ++n)
      b[n] = *(const short8*)(Bs + (wc + n * 16 + (lane & 15)) * 32 + (lane >> 4) * 8);
#pragma unroll
    for (int m = 0; m < 4; ++m)
#pragma unroll
      for (int n = 0; n < 4; ++n)
        acc[m][n] = __builtin_amdgcn_mfma_f32_16x16x32_bf16(a[m], b[n], acc[m][n], 0, 0, 0);
  }

  // epilogue: C row = s (within batch), col = d; store transposed (b,d,s) bf16
  const int bI = r0 >> 12;
  const int sBase = r0 & (NS - 1);
#pragma unroll
  for (int m = 0; m < 4; ++m) {
#pragma unroll
    for (int n = 0; n < 4; ++n) {
      int col = c0 + wc + n * 16 + (lane & 15);
      int srow = sBase + wr + m * 16 + (lane >> 4) * 4;
      f32x4 v = acc[m][n];
      u16x4 o = { f2bf(v[0]), f2bf(v[1]), f2bf(v[2]), f2bf(v[3]) };
      *(u16x4*)(XPT + ((size_t)bI * ND + col) * NS + srow) = o;
    }
  }
}

// ---------------- radix-2 FFT-4096 in LDS (256 threads) ----------------
// DIF: natural in -> bit-reversed out, twiddle e^{-i pi t/m}
__device__ __forceinline__ void fft_dif(float2* z, int tid) {
  for (int m = 2048; m >= 1; m >>= 1) {
    float invm = 1.0f / (float)m;
#pragma unroll
    for (int r = 0; r < 8; ++r) {
      int j = tid + (r << 8);
      int t = j & (m - 1);
      int i0 = ((j & ~(m - 1)) << 1) | t;
      int i1 = i0 + m;
      float2 a = z[i0], b = z[i1];
      float2 s = make_float2(a.x + b.x, a.y + b.y);
      float2 dd = make_float2(a.x - b.x, a.y - b.y);
      float ang = -3.14159265358979323846f * (float)t * invm;
      float sn, cs;
      __sincosf(ang, &sn, &cs);
      z[i0] = s;
      z[i1] = make_float2(dd.x * cs - dd.y * sn, dd.x * sn + dd.y * cs);
    }
    __syncthreads();
  }
}

// DIT inverse (unnormalized): bit-reversed in -> natural out, twiddle e^{+i pi t/m}
__device__ __forceinline__ void fft_dit_inv(float2* z, int tid) {
  for (int m = 1; m <= 2048; m <<= 1) {
    float invm = 1.0f / (float)m;
#pragma unroll
    for (int r = 0; r < 8; ++r) {
      int j = tid + (r << 8);
      int t = j & (m - 1);
      int i0 = ((j & ~(m - 1)) << 1) | t;
      int i1 = i0 + m;
      float2 a = z[i0], b = z[i1];
      float ang = 3.14159265358979323846f * (float)t * invm;
      float sn, cs;
      __sincosf(ang, &sn, &cs);
      float2 bw = make_float2(b.x * cs - b.y * sn, b.x * sn + b.y * cs);
      z[i0] = make_float2(a.x + bw.x, a.y + bw.y);
      z[i1] = make_float2(a.x - bw.x, a.y - bw.y);
    }
    __syncthreads();
  }
}

// ---------------- filter spectra: Hbr[d][p] = bitrev FFT(h_d) * (2/4096) ----------------
__global__ __launch_bounds__(256) void filter_fft(const float* __restrict__ phiT,
                                                  float2* __restrict__ Hbr) {
  __shared__ float2 z[4096];
  const int d = blockIdx.x;
  const int tid = threadIdx.x;
  const float* src = phiT + (size_t)d * NS;
#pragma unroll
  for (int q = 0; q < 8; ++q) {
    int m = tid * 8 + q;
    z[m] = make_float2(src[2 * m], 0.f);       // h[m] = phi_proj[2m, d]
    z[2048 + m] = make_float2(0.f, 0.f);
  }
  __syncthreads();
  fft_dif(z, tid);
  const float sc = 2.0f / 4096.0f;             // x2 (parity) and 1/N (ifft)
#pragma unroll
  for (int r = 0; r < 16; ++r) {
    int p = tid + (r << 8);
    float2 v = z[p];
    Hbr[(size_t)d * 4096 + p] = make_float2(v.x * sc, v.y * sc);
  }
}

// ---------------- main conv: one (b,d) per workgroup ----------------
__global__ __launch_bounds__(256) void conv_kernel(const unsigned short* __restrict__ XPT,
                                                   const float2* __restrict__ Hbr,
                                                   float* __restrict__ outT) {
  __shared__ float2 z[4096];
  const int bd = blockIdx.x;                   // b*768 + d
  const int d = bd % ND;
  const int tid = threadIdx.x;
  const unsigned short* src = XPT + (size_t)bd * NS;

  // z[tau] = (x_proj[2tau], x_proj[2tau+1]), tau<2048; zero-pad above
#pragma unroll
  for (int h = 0; h < 2; ++h) {
    short8 v = *(const short8*)(src + tid * 16 + h * 8);
#pragma unroll
    for (int q = 0; q < 4; ++q) {
      int tau = tid * 8 + h * 4 + q;
      z[tau] = make_float2(bf2f((unsigned short)v[2 * q]),
                           bf2f((unsigned short)v[2 * q + 1]));
    }
  }
#pragma unroll
  for (int q = 0; q < 8; ++q) z[2048 + tid * 8 + q] = make_float2(0.f, 0.f);
  __syncthreads();

  fft_dif(z, tid);

  const float2* H = Hbr + (size_t)d * 4096;
#pragma unroll
  for (int r = 0; r < 16; ++r) {
    int p = tid + (r << 8);
    float2 a = z[p], w = H[p];
    z[p] = make_float2(a.x * w.x - a.y * w.y, a.x * w.y + a.y * w.x);
  }
  __syncthreads();

  fft_dit_inv(z, tid);

  float* dst = outT + (size_t)bd * NS;
#pragma unroll
  for (int q = 0; q < 8; ++q) {
    int tau = tid * 8 + q;
    float2 y = z[tau];
    *(float2*)(dst + 2 * tau) = y;             // out[2tau]=Re, out[2tau+1]=Im
  }
}

// ---------------- transpose outT (B,D,S) -> out (B,S,D) fp32 ----------------
__global__ __launch_bounds__(256) void transpose_out(const float* __restrict__ outT,
                                                     float* __restrict__ out) {
  __shared__ float tile[64][65];
  const int b = blockIdx.z;
  const int d0 = blockIdx.y * 64;
  const int s0 = blockIdx.x * 64;
  const int tid = threadIdx.x;
#pragma unroll
  for (int i = 0; i < 16; ++i) {
    int dd = (tid >> 6) + i * 4;
    int ss = tid & 63;
    tile[dd][ss] = outT[((size_t)b * ND + d0 + dd) * NS + s0 + ss];
  }
  __syncthreads();
#pragma unroll
  for (int i = 0; i < 16; ++i) {
    int ss = (tid >> 6) + i * 4;
    int dd = tid & 63;
    out[((size_t)b * NS + s0 + ss) * ND + d0 + dd] = tile[dd][ss];
  }
}

extern "C" void kernel_launch(void* const* d_in, const int* in_sizes, int n_in,
                              void* d_out, int out_size, void* d_ws, size_t ws_size,
                              hipStream_t stream) {
  const float* x   = (const float*)d_in[0];   // (4,4096,768)
  const float* phi = (const float*)d_in[1];   // (4096,24)
  const float* Mi  = (const float*)d_in[2];   // (768,768)
  const float* Mf  = (const float*)d_in[3];   // (24,768)
  float* out = (float*)d_out;

  // ws layout (96 MB):
  //  [0,24M)   x_projT bf16 (4,768,4096)
  //  [24,48M)  Hbr float2 (768,4096)
  //  [48,96M)  pool: phase1 {x_bf16 24M | MiT 1.2M | phiT 12M} -> phase2 outT fp32 48M
  const size_t SZ_XPT = (size_t)NB * ND * NS * 2;        // 25165824
  const size_t SZ_HBR = (size_t)ND * 4096 * 8;           // 25165824
  const size_t SZ_POOL = (size_t)NB * ND * NS * 4;       // 50331648
  if (ws_size < SZ_XPT + SZ_HBR + SZ_POOL) return;       // fail clean, not OOB

  char* ws = (char*)d_ws;
  unsigned short* xprojT = (unsigned short*)ws;
  float2* Hbr = (float2*)(ws + SZ_XPT);
  char* pool = ws + SZ_XPT + SZ_HBR;
  unsigned short* xbf = (unsigned short*)pool;
  unsigned short* MiT = (unsigned short*)(pool + 25165824);
  float* phiT = (float*)(pool + 25165824 + 1179648);
  float* outT = (float*)pool;                            // reuses phase-1 region

  cast_x_bf16<<<(NB * NS * ND) / (256 * 4), 256, 0, stream>>>(x, xbf);
  transpose_cast_Mi<<<(ND * ND) / 256, 256, 0, stream>>>(Mi, MiT);
  phi_proj_kernel<<<dim3(NS / 256, ND), 256, 0, stream>>>(phi, Mf, phiT);
  gemm_xprojT<<<dim3((NB * NS) / 128, ND / 128), 256, 0, stream>>>(xbf, MiT, xprojT);
  filter_fft<<<ND, 256, 0, stream>>>(phiT, Hbr);
  conv_kernel<<<NB * ND, 256, 0, stream>>>(xprojT, Hbr, outT);
  transpose_out<<<dim3(NS / 64, ND / 64, NB), 256, 0, stream>>>(outT, out);
}

// Round 4
// 136.670 us; speedup vs baseline: 1.6822x; 1.6822x over previous
//
#include <hip/hip_runtime.h>
#include <hip/hip_bf16.h>

// STU spectral conv. out[b,t,d] = 2 * sum_{j even} phi_proj[j,d] x_proj[b,t-j,d].
// Even/odd time split packed as complex -> one FFT-4096 per (b,d).
// FFT-4096 = 16x16x16 radix-16 register FFT, 256 threads, 16 cplx/thread.
// Forward: P1 (DFT over n2 -> pa, twiddle W_4096^{tid*pa}, slot pa*256+tid),
// P2 (DFT over n1 -> pb, twiddle W_256^{n0*pb}, slot pa*256+pb*16+n0),
// P3 (DFT over n0 -> pc, in regs). Pointwise xH in matching reg layout.
// Inverse = exact conj-transpose mirror. Verified by pure-tone traces.
// ROUND-4 FIX: inverse-PC write masked to n2 < 8 (tau < 2048). Complex signal
// has 4096 samples but only tau<2048 map to valid out[2tau],out[2tau+1];
// rounds 2/3 wrote 8192 floats/row, clobbering the next (b,d) row.

#define NB 4
#define NS 4096
#define ND 768
#define NK 24

typedef __attribute__((ext_vector_type(8))) short short8;
typedef __attribute__((ext_vector_type(4))) float f32x4;
typedef __attribute__((ext_vector_type(4))) unsigned short u16x4;

static __device__ __forceinline__ float bf2f(unsigned short u) {
  union { unsigned int i; float f; } v; v.i = ((unsigned int)u) << 16; return v.f;
}
static __device__ __forceinline__ unsigned short f2bf(float f) {
  union { float f; unsigned int i; } v; v.f = f;
  return (unsigned short)((v.i + 0x7fffu + ((v.i >> 16) & 1u)) >> 16);
}

__device__ __forceinline__ float2 cadd(float2 a, float2 b){ return make_float2(a.x+b.x, a.y+b.y); }
__device__ __forceinline__ float2 csub(float2 a, float2 b){ return make_float2(a.x-b.x, a.y-b.y); }
__device__ __forceinline__ float2 cmul(float2 a, float2 b){ return make_float2(a.x*b.x-a.y*b.y, a.x*b.y+a.y*b.x); }

#define C4 0.70710678118654752f
#define C8 0.92387953251128674f
#define S8 0.38268343236508977f
#define TWO_PI 6.28318530717958648f

// DIF 16-pt: natural input, output reg r holds X[bitrev4(r)]
__device__ __forceinline__ void fft16_dif(float2 v[16]) {
  const float twr[8] = {1.f, C8, C4, S8, 0.f, -S8, -C4, -C8};
  const float twi[8] = {0.f, -S8, -C4, -C8, -1.f, -C8, -C4, -S8};
#pragma unroll
  for (int i = 0; i < 8; ++i) {                       // m=8
    float2 a = v[i], b = v[i+8];
    v[i] = cadd(a, b);
    float2 d = csub(a, b);
    v[i+8] = make_float2(d.x*twr[i]-d.y*twi[i], d.x*twi[i]+d.y*twr[i]);
  }
#pragma unroll
  for (int blk = 0; blk < 16; blk += 8)               // m=4
#pragma unroll
    for (int i = 0; i < 4; ++i) {
      float2 a = v[blk+i], b = v[blk+i+4];
      v[blk+i] = cadd(a, b);
      float2 d = csub(a, b);
      v[blk+i+4] = make_float2(d.x*twr[2*i]-d.y*twi[2*i], d.x*twi[2*i]+d.y*twr[2*i]);
    }
#pragma unroll
  for (int blk = 0; blk < 16; blk += 4) {             // m=2 (tw: 1, -i)
    { float2 a = v[blk],   b = v[blk+2]; v[blk] = cadd(a,b);   v[blk+2] = csub(a,b); }
    { float2 a = v[blk+1], b = v[blk+3]; float2 d = csub(a,b);
      v[blk+1] = cadd(a,b); v[blk+3] = make_float2(d.y, -d.x); }
  }
#pragma unroll
  for (int blk = 0; blk < 16; blk += 2) {             // m=1
    float2 a = v[blk], b = v[blk+1];
    v[blk] = cadd(a, b); v[blk+1] = csub(a, b);
  }
}

// conj-transpose mirror (unnormalized): input reg r = X[bitrev4(r)],
// output natural y[n] = sum_k X[k] W^{+nk}
__device__ __forceinline__ void idft16(float2 v[16]) {
  const float twr[8] = {1.f, C8, C4, S8, 0.f, -S8, -C4, -C8};
  const float twi[8] = {0.f, S8, C4, C8, 1.f, C8, C4, S8};     // conj
#pragma unroll
  for (int blk = 0; blk < 16; blk += 2) {             // m=1
    float2 a = v[blk], b = v[blk+1];
    v[blk] = cadd(a, b); v[blk+1] = csub(a, b);
  }
#pragma unroll
  for (int blk = 0; blk < 16; blk += 4) {             // m=2 (tw: 1, +i)
    { float2 a = v[blk],   b = v[blk+2]; v[blk] = cadd(a,b);   v[blk+2] = csub(a,b); }
    { float2 a = v[blk+1], b = v[blk+3]; float2 t = make_float2(-b.y, b.x);
      v[blk+1] = cadd(a,t); v[blk+3] = csub(a,t); }
  }
#pragma unroll
  for (int blk = 0; blk < 16; blk += 8)               // m=4
#pragma unroll
    for (int i = 0; i < 4; ++i) {
      float2 b = v[blk+i+4];
      float2 t = make_float2(b.x*twr[2*i]-b.y*twi[2*i], b.x*twi[2*i]+b.y*twr[2*i]);
      float2 a = v[blk+i];
      v[blk+i] = cadd(a, t); v[blk+i+4] = csub(a, t);
    }
#pragma unroll
  for (int i = 0; i < 8; ++i) {                       // m=8
    float2 b = v[i+8];
    float2 t = make_float2(b.x*twr[i]-b.y*twi[i], b.x*twi[i]+b.y*twr[i]);
    float2 a = v[i];
    v[i] = cadd(a, t); v[i+8] = csub(a, t);
  }
}

#define BR_TABLE {0,8,4,12,2,10,6,14,1,9,5,13,3,11,7,15}
#define PAD(i) ((i) + ((i) >> 4))

// ---------------- cast x (fp32 -> bf16) ----------------
__global__ __launch_bounds__(256) void cast_x_bf16(const float* __restrict__ in,
                                                   unsigned short* __restrict__ out) {
  int i = (blockIdx.x * 256 + threadIdx.x) * 4;
  float4 v = *(const float4*)(in + i);
  u16x4 o = { f2bf(v.x), f2bf(v.y), f2bf(v.z), f2bf(v.w) };
  *(u16x4*)(out + i) = o;
}

// ---------------- MiT[d][e] = bf16(Mi[e][d]) ----------------
__global__ __launch_bounds__(256) void transpose_cast_Mi(const float* __restrict__ Mi,
                                                         unsigned short* __restrict__ MiT) {
  int idx = blockIdx.x * 256 + threadIdx.x;
  int d = idx / ND, e = idx % ND;
  MiT[idx] = f2bf(Mi[e * ND + d]);
}

// ---------------- phiE[d][m] = phi_proj[2m, d], m<2048 (even rows only) ----------------
__global__ __launch_bounds__(256) void phi_proj_kernel(const float* __restrict__ phi,
                                                       const float* __restrict__ Mf,
                                                       float* __restrict__ phiE) {
  int d = blockIdx.y;
  int m = blockIdx.x * 256 + threadIdx.x;    // 0..2047
  int s = 2 * m;
  float acc = 0.f;
#pragma unroll
  for (int k = 0; k < NK; ++k) acc += phi[s * NK + k] * Mf[k * ND + d];
  phiE[d * 2048 + m] = acc;
}

// ---------------- GEMM (round-1 reg-staged, HW-proven) ----------------
__global__ __launch_bounds__(256) void gemm_xprojT(const unsigned short* __restrict__ Xb,
                                                   const unsigned short* __restrict__ MiT,
                                                   unsigned short* __restrict__ XPT) {
  __shared__ unsigned short As[128 * 32];
  __shared__ unsigned short Bs[128 * 32];
  const int tid = threadIdx.x;
  const int r0 = blockIdx.x * 128;      // global row in [0,16384)
  const int c0 = blockIdx.y * 128;      // d
  const int lane = tid & 63;
  const int wave = tid >> 6;
  const int wr = (wave >> 1) * 64;
  const int wc = (wave & 1) * 64;

  f32x4 acc[4][4];
#pragma unroll
  for (int m = 0; m < 4; ++m)
#pragma unroll
    for (int n = 0; n < 4; ++n) acc[m][n] = (f32x4){0.f, 0.f, 0.f, 0.f};

  for (int k0 = 0; k0 < ND; k0 += 32) {
    short8 va[2], vb[2];
#pragma unroll
    for (int i = 0; i < 2; ++i) {
      int slot = tid + 256 * i;
      int row = slot >> 2, kc = slot & 3;
      va[i] = *(const short8*)(Xb + (size_t)(r0 + row) * ND + k0 + kc * 8);
      vb[i] = *(const short8*)(MiT + (size_t)(c0 + row) * ND + k0 + kc * 8);
    }
    __syncthreads();
#pragma unroll
    for (int i = 0; i < 2; ++i) {
      int slot = tid + 256 * i;
      *(short8*)(As + slot * 8) = va[i];
      *(short8*)(Bs + slot * 8) = vb[i];
    }
    __syncthreads();

    short8 a[4], b[4];
#pragma unroll
    for (int m = 0; m < 4; ++m)
      a[m] = *(const short8*)(As + (wr + m * 16 + (lane & 15)) * 32 + (lane >> 4) * 8);
#pragma unroll
    for (int n = 0; n < 4; ++n)
      b[n] = *(const short8*)(Bs + (wc + n * 16 + (lane & 15)) * 32 + (lane >> 4) * 8);
#pragma unroll
    for (int m = 0; m < 4; ++m)
#pragma unroll
      for (int n = 0; n < 4; ++n)
        acc[m][n] = __builtin_amdgcn_mfma_f32_16x16x32_bf16(a[m], b[n], acc[m][n], 0, 0, 0);
  }

  const int bI = r0 >> 12;
  const int sBase = r0 & (NS - 1);
#pragma unroll
  for (int m = 0; m < 4; ++m) {
#pragma unroll
    for (int n = 0; n < 4; ++n) {
      int col = c0 + wc + n * 16 + (lane & 15);
      int srow = sBase + wr + m * 16 + (lane >> 4) * 4;
      f32x4 v = acc[m][n];
      u16x4 o = { f2bf(v[0]), f2bf(v[1]), f2bf(v[2]), f2bf(v[3]) };
      *(u16x4*)(XPT + ((size_t)bI * ND + col) * NS + srow) = o;
    }
  }
}

// ---------------- filter spectra: H[d][r*256+tid] = fft4096(h_d) * (2/4096) ----------------
__global__ __launch_bounds__(256) void filter_fft(const float* __restrict__ phiE,
                                                  float2* __restrict__ Hbr) {
  __shared__ float LR[4352], LI[4352];
  const int d = blockIdx.x;
  const int tid = threadIdx.x;
  const int BR[16] = BR_TABLE;
  float2 v[16];
  const float* src = phiE + (size_t)d * 2048;
#pragma unroll
  for (int n2 = 0; n2 < 16; ++n2)
    v[n2] = (n2 < 8) ? make_float2(src[n2 * 256 + tid], 0.f) : make_float2(0.f, 0.f);

  float sn, cs;
  // P1: DFT over n2 -> pa, twiddle W_4096^{tid*pa}, slot pa*256+tid
  fft16_dif(v);
  __sincosf(-(TWO_PI / 4096.f) * (float)tid, &sn, &cs);
  { float2 step = make_float2(cs, sn), w = make_float2(1.f, 0.f);
#pragma unroll
    for (int p = 1; p < 16; ++p) { w = cmul(w, step); v[BR[p]] = cmul(v[BR[p]], w); } }
#pragma unroll
  for (int r = 0; r < 16; ++r) { int i = BR[r] * 256 + tid; int s = PAD(i); LR[s] = v[r].x; LI[s] = v[r].y; }
  __syncthreads();

  // P2: thread (pa,n0), DFT over n1 -> pb, twiddle W_256^{n0*pb}
  const int p2 = tid >> 4, n0 = tid & 15;
#pragma unroll
  for (int n1 = 0; n1 < 16; ++n1) { int i = p2 * 256 + n1 * 16 + n0; int s = PAD(i); v[n1] = make_float2(LR[s], LI[s]); }
  fft16_dif(v);
  __sincosf(-(TWO_PI / 256.f) * (float)n0, &sn, &cs);
  { float2 step = make_float2(cs, sn), w = make_float2(1.f, 0.f);
#pragma unroll
    for (int p = 1; p < 16; ++p) { w = cmul(w, step); v[BR[p]] = cmul(v[BR[p]], w); } }
  __syncthreads();
#pragma unroll
  for (int r = 0; r < 16; ++r) { int i = p2 * 256 + BR[r] * 16 + n0; int s = PAD(i); LR[s] = v[r].x; LI[s] = v[r].y; }
  __syncthreads();

  // P3: thread (pa,pb)=tid, DFT over n0 -> pc (regs); store H lane-coalesced
#pragma unroll
  for (int q = 0; q < 16; ++q) { int i = tid * 16 + q; int s = PAD(i); v[q] = make_float2(LR[s], LI[s]); }
  fft16_dif(v);
  const float sc = 2.0f / 4096.0f;
  float2* H = Hbr + (size_t)d * 4096;
#pragma unroll
  for (int r = 0; r < 16; ++r)
    H[r * 256 + tid] = make_float2(v[r].x * sc, v[r].y * sc);
}

// ---------------- main conv: one (b,d) per workgroup ----------------
__global__ __launch_bounds__(256) void conv_kernel(const unsigned short* __restrict__ XPT,
                                                   const float2* __restrict__ Hbr,
                                                   float* __restrict__ outT) {
  __shared__ float LR[4352], LI[4352];
  const int bd = blockIdx.x;
  const int d = bd % ND;
  const int tid = threadIdx.x;
  const int BR[16] = BR_TABLE;
  float2 v[16];
  float sn, cs;

  // load: z[n] = (x[2n], x[2n+1]) bf16 pair as one dword; n >= 2048 zero
  const unsigned int* src = (const unsigned int*)(XPT + (size_t)bd * NS);
#pragma unroll
  for (int n2 = 0; n2 < 16; ++n2) {
    if (n2 < 8) {
      unsigned int w = src[n2 * 256 + tid];
      v[n2] = make_float2(bf2f((unsigned short)(w & 0xffffu)), bf2f((unsigned short)(w >> 16)));
    } else v[n2] = make_float2(0.f, 0.f);
  }

  // ---- forward P1 ----
  fft16_dif(v);
  __sincosf(-(TWO_PI / 4096.f) * (float)tid, &sn, &cs);
  { float2 step = make_float2(cs, sn), w = make_float2(1.f, 0.f);
#pragma unroll
    for (int p = 1; p < 16; ++p) { w = cmul(w, step); v[BR[p]] = cmul(v[BR[p]], w); } }
#pragma unroll
  for (int r = 0; r < 16; ++r) { int i = BR[r] * 256 + tid; int s = PAD(i); LR[s] = v[r].x; LI[s] = v[r].y; }
  __syncthreads();

  // ---- forward P2 ----
  const int p2 = tid >> 4, n0 = tid & 15;
#pragma unroll
  for (int n1 = 0; n1 < 16; ++n1) { int i = p2 * 256 + n1 * 16 + n0; int s = PAD(i); v[n1] = make_float2(LR[s], LI[s]); }
  fft16_dif(v);
  __sincosf(-(TWO_PI / 256.f) * (float)n0, &sn, &cs);
  { float2 step = make_float2(cs, sn), w = make_float2(1.f, 0.f);
#pragma unroll
    for (int p = 1; p < 16; ++p) { w = cmul(w, step); v[BR[p]] = cmul(v[BR[p]], w); } }
  __syncthreads();
#pragma unroll
  for (int r = 0; r < 16; ++r) { int i = p2 * 256 + BR[r] * 16 + n0; int s = PAD(i); LR[s] = v[r].x; LI[s] = v[r].y; }
  __syncthreads();

  // ---- forward P3 + pointwise*H + inverse PA: all in registers ----
#pragma unroll
  for (int q = 0; q < 16; ++q) { int i = tid * 16 + q; int s = PAD(i); v[q] = make_float2(LR[s], LI[s]); }
  fft16_dif(v);
  const float2* H = Hbr + (size_t)d * 4096;
#pragma unroll
  for (int r = 0; r < 16; ++r) v[r] = cmul(v[r], H[r * 256 + tid]);
  idft16(v);                                   // -> natural n0 in regs
  __sincosf((TWO_PI / 256.f) * (float)(tid & 15), &sn, &cs);   // conj twiddle, pb = tid&15
  { float2 step = make_float2(cs, sn), w = make_float2(1.f, 0.f);
#pragma unroll
    for (int n = 1; n < 16; ++n) { w = cmul(w, step); v[n] = cmul(v[n], w); } }
#pragma unroll
  for (int n = 0; n < 16; ++n) { int i = tid * 16 + n; int s = PAD(i); LR[s] = v[n].x; LI[s] = v[n].y; }
  __syncthreads();

  // ---- inverse PB: thread (pa,n0), IDFT over pb -> n1; twiddle W^{-(16n1+n0)pa} ----
#pragma unroll
  for (int r = 0; r < 16; ++r) { int i = p2 * 256 + BR[r] * 16 + n0; int s = PAD(i); v[r] = make_float2(LR[s], LI[s]); }
  idft16(v);                                   // -> natural n1
  {
    float sn0, cs0;
    __sincosf((TWO_PI / 4096.f) * (float)(n0 * p2), &sn0, &cs0);
    __sincosf((TWO_PI / 256.f) * (float)p2, &sn, &cs);
    float2 step = make_float2(cs, sn), w = make_float2(cs0, sn0);
    v[0] = cmul(v[0], w);
#pragma unroll
    for (int n = 1; n < 16; ++n) { w = cmul(w, step); v[n] = cmul(v[n], w); }
  }
  __syncthreads();
#pragma unroll
  for (int n = 0; n < 16; ++n) { int i = p2 * 256 + n * 16 + n0; int s = PAD(i); LR[s] = v[n].x; LI[s] = v[n].y; }
  __syncthreads();

  // ---- inverse PC: thread tid, IDFT over pa -> natural n2; write global ----
  // FIX: only n2 < 8 (tau < 2048) are valid outputs; writing all 16 overran
  // the 4096-float row by 4096 floats, clobbering the next (b,d) row.
#pragma unroll
  for (int r = 0; r < 16; ++r) { int i = BR[r] * 256 + tid; int s = PAD(i); v[r] = make_float2(LR[s], LI[s]); }
  idft16(v);
  float* dst = outT + (size_t)bd * NS;
#pragma unroll
  for (int n2 = 0; n2 < 8; ++n2)
    *(float2*)(dst + ((n2 << 8) + tid) * 2) = v[n2];   // (out[2n], out[2n+1]), n < 2048
}

// ---------------- transpose outT (B,D,S) -> out (B,S,D) fp32 ----------------
__global__ __launch_bounds__(256) void transpose_out(const float* __restrict__ outT,
                                                     float* __restrict__ out) {
  __shared__ float tile[64][65];
  const int b = blockIdx.z;
  const int d0 = blockIdx.y * 64;
  const int s0 = blockIdx.x * 64;
  const int tid = threadIdx.x;
#pragma unroll
  for (int i = 0; i < 16; ++i) {
    int dd = (tid >> 6) + i * 4;
    int ss = tid & 63;
    tile[dd][ss] = outT[((size_t)b * ND + d0 + dd) * NS + s0 + ss];
  }
  __syncthreads();
#pragma unroll
  for (int i = 0; i < 16; ++i) {
    int ss = (tid >> 6) + i * 4;
    int dd = tid & 63;
    out[((size_t)b * NS + s0 + ss) * ND + d0 + dd] = tile[dd][ss];
  }
}

extern "C" void kernel_launch(void* const* d_in, const int* in_sizes, int n_in,
                              void* d_out, int out_size, void* d_ws, size_t ws_size,
                              hipStream_t stream) {
  const float* x   = (const float*)d_in[0];
  const float* phi = (const float*)d_in[1];
  const float* Mi  = (const float*)d_in[2];
  const float* Mf  = (const float*)d_in[3];
  float* out = (float*)d_out;

  const size_t SZ_XPT = (size_t)NB * ND * NS * 2;        // 24 MB
  const size_t SZ_HBR = (size_t)ND * 4096 * 8;           // 24 MB
  const size_t SZ_POOL = (size_t)NB * ND * NS * 4;       // 48 MB
  if (ws_size < SZ_XPT + SZ_HBR + SZ_POOL) return;

  char* ws = (char*)d_ws;
  unsigned short* xprojT = (unsigned short*)ws;
  float2* Hbr = (float2*)(ws + SZ_XPT);
  char* pool = ws + SZ_XPT + SZ_HBR;
  unsigned short* xbf = (unsigned short*)pool;
  unsigned short* MiT = (unsigned short*)(pool + 25165824);
  float* phiE = (float*)(pool + 25165824 + 1179648);
  float* outT = (float*)pool;                            // reuses phase-1 region

  cast_x_bf16<<<(NB * NS * ND) / (256 * 4), 256, 0, stream>>>(x, xbf);
  transpose_cast_Mi<<<(ND * ND) / 256, 256, 0, stream>>>(Mi, MiT);
  phi_proj_kernel<<<dim3(2048 / 256, ND), 256, 0, stream>>>(phi, Mf, phiE);
  gemm_xprojT<<<dim3((NB * NS) / 128, ND / 128), 256, 0, stream>>>(xbf, MiT, xprojT);
  filter_fft<<<ND, 256, 0, stream>>>(phiE, Hbr);
  conv_kernel<<<NB * ND, 256, 0, stream>>>(xprojT, Hbr, outT);
  transpose_out<<<dim3(NS / 64, ND / 64, NB), 256, 0, stream>>>(outT, out);
}